// Round 1
// baseline (568.209 us; speedup 1.0000x reference)
//
#include <hip/hip_runtime.h>
#include <cstdint>

#define B_    128
#define T_    2048
#define NIN_  16
#define NH_   128
#define NOUT_ 5

#define ALPHA_I_ 0.75f
#define ALPHA_V_ 0.96875f
#define THETA_   64.0f

__device__ __forceinline__ float mulrn(float a, float b) { return __fmul_rn(a, b); }
__device__ __forceinline__ float addrn(float a, float b) { return __fadd_rn(a, b); }

// ---------------------------------------------------------------------------
// prep: weight_norm (x64 folded in), delay tables (effective shift = d0+1,
// folding delay_shift1), zero the 3 count slots of d_out.
// ---------------------------------------------------------------------------
__global__ void prep_kernel(const float* __restrict__ fc1_v, const float* __restrict__ fc1_g,
                            const float* __restrict__ fc2_v, const float* __restrict__ fc2_g,
                            const float* __restrict__ fc3_v, const float* __restrict__ fc3_g,
                            const float* __restrict__ delay1, const float* __restrict__ delay2,
                            float* __restrict__ w1s, float* __restrict__ w2s, float* __restrict__ w3s,
                            int* __restrict__ d0_1, float* __restrict__ f_1,
                            int* __restrict__ d0_2, float* __restrict__ f_2,
                            float* __restrict__ counts) {
  int tid = threadIdx.x;
  if (tid < NH_) {
    // layer 1 row
    {
      float ss = 0.f;
      for (int c = 0; c < NIN_; c++) { float v = fc1_v[tid * NIN_ + c]; ss = __fmaf_rn(v, v, ss); }
      float nrm = sqrtf(ss);
      float g = fc1_g[tid];
      for (int c = 0; c < NIN_; c++)
        w1s[tid * NIN_ + c] = 64.0f * __fdiv_rn(mulrn(g, fc1_v[tid * NIN_ + c]), nrm);
    }
    // layer 2 row
    {
      float ss = 0.f;
      for (int c = 0; c < NH_; c++) { float v = fc2_v[tid * NH_ + c]; ss = __fmaf_rn(v, v, ss); }
      float nrm = sqrtf(ss);
      float g = fc2_g[tid];
      for (int c = 0; c < NH_; c++)
        w2s[tid * NH_ + c] = 64.0f * __fdiv_rn(mulrn(g, fc2_v[tid * NH_ + c]), nrm);
    }
    // delay tables: effective integer shift includes the +1 of delay_shift1
    {
      float d1 = delay1[tid];
      float fl = floorf(d1);
      d0_1[tid] = (int)fl + 1;
      f_1[tid] = __fsub_rn(d1, fl);
      float d2 = delay2[tid];
      float fl2 = floorf(d2);
      d0_2[tid] = (int)fl2 + 1;
      f_2[tid] = __fsub_rn(d2, fl2);
    }
  }
  if (tid < NOUT_) {
    float ss = 0.f;
    for (int c = 0; c < NH_; c++) { float v = fc3_v[tid * NH_ + c]; ss = __fmaf_rn(v, v, ss); }
    float nrm = sqrtf(ss);
    float g = fc3_g[tid];
    for (int c = 0; c < NH_; c++)
      w3s[tid * NH_ + c] = 64.0f * __fdiv_rn(mulrn(g, fc3_v[tid * NH_ + c]), nrm);
  }
  if (tid < 3) counts[tid] = 0.f;
}

// ---------------------------------------------------------------------------
// gemm1: z[b,o,t] = sum_c w1s[o,c] * x[b,c,t]   (x is the raw input spikes)
// grid (T/256, B), block 256 (t-parallel)
// ---------------------------------------------------------------------------
__global__ __launch_bounds__(256) void gemm1_kernel(const float* __restrict__ x,
                                                    const float* __restrict__ w1s,
                                                    float* __restrict__ z) {
  __shared__ float w[NH_ * NIN_];
  int tid = threadIdx.x;
  for (int i = tid; i < NH_ * NIN_; i += 256) w[i] = w1s[i];
  __syncthreads();
  int t = blockIdx.x * 256 + tid;
  int b = blockIdx.y;
  const float* xp = x + (size_t)b * NIN_ * T_ + t;
  float xv[NIN_];
#pragma unroll
  for (int c = 0; c < NIN_; c++) xv[c] = xp[(size_t)c * T_];
  float* zp = z + (size_t)b * NH_ * T_ + t;
  for (int o = 0; o < NH_; o++) {
    float acc = 0.f;
#pragma unroll
    for (int c = 0; c < NIN_; c++) acc = __fmaf_rn(w[o * NIN_ + c], xv[c], acc);
    zp[(size_t)o * T_] = acc;
  }
}

// ---------------------------------------------------------------------------
// gemm with fused axon-delay gather (for layers 2 and 3).
// s holds UNSHIFTED u8 spikes; effective shift table already includes +1.
//   val_c(t) = (1-f_c)*s[c, t-e_c] + f_c*s[c, t-e_c-1]   (taps masked if <0)
// grid (T/256, O/OT, B), block 256 (t-parallel), OT outputs per thread.
// ---------------------------------------------------------------------------
template <int OT>
__global__ __launch_bounds__(256) void gemm_delay_kernel(const uint8_t* __restrict__ s,
                                                         const float* __restrict__ ws,
                                                         const int* __restrict__ d0c,
                                                         const float* __restrict__ fc,
                                                         float* __restrict__ z) {
  __shared__ float w[OT][NH_];
  __shared__ int sd0[NH_];
  __shared__ float sf[NH_];
  __shared__ float somf[NH_];
  int tid = threadIdx.x;
  int otile = blockIdx.y * OT;
  int b = blockIdx.z;
  for (int i = tid; i < OT * NH_; i += 256)
    w[i / NH_][i % NH_] = ws[(size_t)(otile + i / NH_) * NH_ + (i % NH_)];
  for (int i = tid; i < NH_; i += 256) {
    sd0[i] = d0c[i];
    float f = fc[i];
    sf[i] = f;
    somf[i] = __fsub_rn(1.0f, f);
  }
  __syncthreads();
  int t = blockIdx.x * 256 + tid;
  const uint8_t* sp = s + (size_t)b * NH_ * T_;
  float acc[OT];
#pragma unroll
  for (int oo = 0; oo < OT; oo++) acc[oo] = 0.f;
  for (int c = 0; c < NH_; c++) {
    int ta = t - sd0[c];
    int i0 = ta < 0 ? 0 : ta;        // clamped addresses (always in-bounds)
    int i1 = ta < 1 ? 0 : ta - 1;
    float a  = (float)sp[(size_t)c * T_ + i0];
    float b2 = (float)sp[(size_t)c * T_ + i1];
    a  = (ta >= 0) ? a  : 0.f;
    b2 = (ta >= 1) ? b2 : 0.f;
    float val = addrn(mulrn(somf[c], a), mulrn(sf[c], b2));
#pragma unroll
    for (int oo = 0; oo < OT; oo++) acc[oo] = __fmaf_rn(w[oo][c], val, acc[oo]);
  }
  float* zp = z + ((size_t)b * (gridDim.y * OT) + otile) * T_ + t;
#pragma unroll
  for (int oo = 0; oo < OT; oo++) zp[(size_t)oo * T_] = acc[oo];
}

// ---------------------------------------------------------------------------
// Loihi scan, u8 spike output (UNSHIFTED), bit-packed 16B stores.
// One thread per (b,o) row; 64-timestep groups with one-group-ahead prefetch.
// count = sum of spikes for t in [0, T-2]  (== sum(delay_shift1(s)))
// ---------------------------------------------------------------------------
__global__ __launch_bounds__(64) void scan_u8_kernel(const float* __restrict__ z,
                                                     uint8_t* __restrict__ s,
                                                     float* __restrict__ cnt) {
  int row = blockIdx.x * 64 + threadIdx.x;
  const float4* zp4 = (const float4*)(z + (size_t)row * T_);
  uint8_t* sp = s + (size_t)row * T_;
  float u = 0.f, v = 0.f, c = 0.f, last_s = 0.f;
  float4 cur[16], nxt[16];
#pragma unroll
  for (int i = 0; i < 16; i++) cur[i] = zp4[i];
  for (int g = 0; g < T_ / 64; g++) {
    if (g + 1 < T_ / 64) {
#pragma unroll
      for (int i = 0; i < 16; i++) nxt[i] = zp4[(g + 1) * 16 + i];
    }
    uint32_t packs[16];
#pragma unroll
    for (int i = 0; i < 16; i++) {
      float zv[4] = {cur[i].x, cur[i].y, cur[i].z, cur[i].w};
      uint32_t p = 0;
#pragma unroll
      for (int j = 0; j < 4; j++) {
        u = addrn(mulrn(ALPHA_I_, u), zv[j]);
        v = addrn(mulrn(ALPHA_V_, v), u);
        uint32_t sbit = (v >= THETA_) ? 1u : 0u;
        v = sbit ? 0.f : v;
        p |= sbit << (8 * j);
        last_s = (float)sbit;
        c += (float)sbit;
      }
      packs[i] = p;
    }
    uint4* dst = (uint4*)(sp + g * 64);
#pragma unroll
    for (int i = 0; i < 4; i++)
      dst[i] = make_uint4(packs[4 * i], packs[4 * i + 1], packs[4 * i + 2], packs[4 * i + 3]);
#pragma unroll
    for (int i = 0; i < 16; i++) cur[i] = nxt[i];
  }
  c -= last_s;  // exclude t = T-1 (delay_shift1 drops it)
  for (int off = 32; off; off >>= 1) c += __shfl_down(c, off, 64);
  if (threadIdx.x == 0) atomicAdd(cnt, c);
}

// ---------------------------------------------------------------------------
// Loihi scan, f32 SHIFTED output straight into d_out (layer 3).
// ---------------------------------------------------------------------------
__global__ __launch_bounds__(64) void scan_f32_kernel(const float* __restrict__ z,
                                                      float* __restrict__ out,
                                                      float* __restrict__ cnt) {
  int row = blockIdx.x * 64 + threadIdx.x;
  const float4* zp4 = (const float4*)(z + (size_t)row * T_);
  float* op = out + (size_t)row * T_;
  float u = 0.f, v = 0.f, c = 0.f;
  op[0] = 0.f;
  float4 cur[16], nxt[16];
#pragma unroll
  for (int i = 0; i < 16; i++) cur[i] = zp4[i];
  for (int g = 0; g < T_ / 64; g++) {
    if (g + 1 < T_ / 64) {
#pragma unroll
      for (int i = 0; i < 16; i++) nxt[i] = zp4[(g + 1) * 16 + i];
    }
#pragma unroll
    for (int i = 0; i < 16; i++) {
      float zv[4] = {cur[i].x, cur[i].y, cur[i].z, cur[i].w};
#pragma unroll
      for (int j = 0; j < 4; j++) {
        int t = g * 64 + i * 4 + j;
        u = addrn(mulrn(ALPHA_I_, u), zv[j]);
        v = addrn(mulrn(ALPHA_V_, v), u);
        float sv = (v >= THETA_) ? 1.f : 0.f;
        v = (sv != 0.f) ? 0.f : v;
        if (t < T_ - 1) {
          op[t + 1] = sv;  // shifted store
          c += sv;
        }
      }
    }
#pragma unroll
    for (int i = 0; i < 16; i++) cur[i] = nxt[i];
  }
  for (int off = 32; off; off >>= 1) c += __shfl_down(c, off, 64);
  if (threadIdx.x == 0) atomicAdd(cnt, c);
}

// ---------------------------------------------------------------------------
extern "C" void kernel_launch(void* const* d_in, const int* in_sizes, int n_in,
                              void* d_out, int out_size, void* d_ws, size_t ws_size,
                              hipStream_t stream) {
  (void)in_sizes; (void)n_in; (void)out_size; (void)ws_size;
  const float* spike  = (const float*)d_in[0];
  const float* fc1_v  = (const float*)d_in[1];
  const float* fc1_g  = (const float*)d_in[2];
  const float* fc2_v  = (const float*)d_in[3];
  const float* fc2_g  = (const float*)d_in[4];
  const float* fc3_v  = (const float*)d_in[5];
  const float* fc3_g  = (const float*)d_in[6];
  const float* delay1 = (const float*)d_in[7];
  const float* delay2 = (const float*)d_in[8];
  float* out = (float*)d_out;

  float* ws   = (float*)d_ws;
  float* w1s  = ws;                         // 2048 floats
  float* w2s  = w1s + 2048;                 // 16384
  float* w3s  = w2s + 16384;                // 640
  int*   d01  = (int*)(w3s + 640);          // 128
  float* f1   = (float*)(d01 + 128);        // 128
  int*   d02  = (int*)(f1 + 128);           // 128
  float* f2   = (float*)(d02 + 128);        // 128
  float* zbuf = ws + 20480;                 // B*NH*T floats (134.2 MB), 16B-aligned
  uint8_t* sbuf = (uint8_t*)(zbuf + (size_t)B_ * NH_ * T_);  // B*NH*T bytes
  float* counts = out + (size_t)B_ * NOUT_ * T_;

  prep_kernel<<<1, 128, 0, stream>>>(fc1_v, fc1_g, fc2_v, fc2_g, fc3_v, fc3_g,
                                     delay1, delay2, w1s, w2s, w3s, d01, f1, d02, f2, counts);

  // layer 1
  gemm1_kernel<<<dim3(T_ / 256, B_), 256, 0, stream>>>(spike, w1s, zbuf);
  scan_u8_kernel<<<dim3(B_ * NH_ / 64), 64, 0, stream>>>(zbuf, sbuf, counts + 0);

  // layer 2 (axon delay 1 fused into gather)
  gemm_delay_kernel<16><<<dim3(T_ / 256, NH_ / 16, B_), 256, 0, stream>>>(sbuf, w2s, d01, f1, zbuf);
  scan_u8_kernel<<<dim3(B_ * NH_ / 64), 64, 0, stream>>>(zbuf, sbuf, counts + 1);

  // layer 3 (axon delay 2 fused into gather)
  gemm_delay_kernel<5><<<dim3(T_ / 256, 1, B_), 256, 0, stream>>>(sbuf, w3s, d02, f2, zbuf);
  scan_f32_kernel<<<dim3(B_ * NOUT_ / 64), 64, 0, stream>>>(zbuf, out, counts + 2);
}

// Round 2
// 381.519 us; speedup vs baseline: 1.4893x; 1.4893x over previous
//
#include <hip/hip_runtime.h>
#include <cstdint>

#define B_    128
#define T_    2048
#define NIN_  16
#define NH_   128
#define NOUT_ 5

#define ALPHA_I_ 0.75f
#define ALPHA_V_ 0.96875f
#define THETA_   64.0f

__device__ __forceinline__ float mulrn(float a, float b) { return __fmul_rn(a, b); }
__device__ __forceinline__ float addrn(float a, float b) { return __fadd_rn(a, b); }

// ---------------------------------------------------------------------------
// prep: weight_norm (x64 folded in), delay tables (effective shift = d0+1,
// folding delay_shift1), zero the 3 count slots of d_out.
// ---------------------------------------------------------------------------
__global__ void prep_kernel(const float* __restrict__ fc1_v, const float* __restrict__ fc1_g,
                            const float* __restrict__ fc2_v, const float* __restrict__ fc2_g,
                            const float* __restrict__ fc3_v, const float* __restrict__ fc3_g,
                            const float* __restrict__ delay1, const float* __restrict__ delay2,
                            float* __restrict__ w1s, float* __restrict__ w2s, float* __restrict__ w3s,
                            int* __restrict__ d0_1, float* __restrict__ f_1,
                            int* __restrict__ d0_2, float* __restrict__ f_2,
                            float* __restrict__ counts) {
  int tid = threadIdx.x;
  if (tid < NH_) {
    {
      float ss = 0.f;
      for (int c = 0; c < NIN_; c++) { float v = fc1_v[tid * NIN_ + c]; ss = __fmaf_rn(v, v, ss); }
      float nrm = sqrtf(ss);
      float g = fc1_g[tid];
      for (int c = 0; c < NIN_; c++)
        w1s[tid * NIN_ + c] = 64.0f * __fdiv_rn(mulrn(g, fc1_v[tid * NIN_ + c]), nrm);
    }
    {
      float ss = 0.f;
      for (int c = 0; c < NH_; c++) { float v = fc2_v[tid * NH_ + c]; ss = __fmaf_rn(v, v, ss); }
      float nrm = sqrtf(ss);
      float g = fc2_g[tid];
      for (int c = 0; c < NH_; c++)
        w2s[tid * NH_ + c] = 64.0f * __fdiv_rn(mulrn(g, fc2_v[tid * NH_ + c]), nrm);
    }
    {
      float d1 = delay1[tid];
      float fl = floorf(d1);
      d0_1[tid] = (int)fl + 1;
      f_1[tid] = __fsub_rn(d1, fl);
      float d2 = delay2[tid];
      float fl2 = floorf(d2);
      d0_2[tid] = (int)fl2 + 1;
      f_2[tid] = __fsub_rn(d2, fl2);
    }
  }
  if (tid < NOUT_) {
    float ss = 0.f;
    for (int c = 0; c < NH_; c++) { float v = fc3_v[tid * NH_ + c]; ss = __fmaf_rn(v, v, ss); }
    float nrm = sqrtf(ss);
    float g = fc3_g[tid];
    for (int c = 0; c < NH_; c++)
      w3s[tid * NH_ + c] = 64.0f * __fdiv_rn(mulrn(g, fc3_v[tid * NH_ + c]), nrm);
  }
  if (tid < 3) counts[tid] = 0.f;
}

// ---------------------------------------------------------------------------
// gemm1: z[b,o,t] = sum_c w1s[o,c] * x[b,c,t]
// ---------------------------------------------------------------------------
__global__ __launch_bounds__(256) void gemm1_kernel(const float* __restrict__ x,
                                                    const float* __restrict__ w1s,
                                                    float* __restrict__ z) {
  __shared__ float w[NH_ * NIN_];
  int tid = threadIdx.x;
  for (int i = tid; i < NH_ * NIN_; i += 256) w[i] = w1s[i];
  __syncthreads();
  int t = blockIdx.x * 256 + tid;
  int b = blockIdx.y;
  const float* xp = x + (size_t)b * NIN_ * T_ + t;
  float xv[NIN_];
#pragma unroll
  for (int c = 0; c < NIN_; c++) xv[c] = xp[(size_t)c * T_];
  float* zp = z + (size_t)b * NH_ * T_ + t;
  for (int o = 0; o < NH_; o++) {
    float acc = 0.f;
#pragma unroll
    for (int c = 0; c < NIN_; c++) acc = __fmaf_rn(w[o * NIN_ + c], xv[c], acc);
    zp[(size_t)o * T_] = acc;
  }
}

// ---------------------------------------------------------------------------
// gemm with fused axon-delay gather, BITPACKED spike input.
// sbits: per row (b,c) 64 u32 words (2048 bits). Effective shift e includes
// the +1 of delay_shift1. val(c,t) = omf_c*s[c,t-e] + f_c*s[c,t-e-1].
// Block: 256 threads, each handles 4 contiguous t's and OT outputs.
// grid (T/1024, O/OT, B).
// ---------------------------------------------------------------------------
template <int OT>
__global__ __launch_bounds__(256) void gemm_delay_bits_kernel(const uint32_t* __restrict__ sbits,
                                                              const float* __restrict__ ws,
                                                              const int* __restrict__ d0c,
                                                              const float* __restrict__ fc,
                                                              float* __restrict__ z,
                                                              int o_count) {
  __shared__ float s_w[NH_ * OT];      // transposed: s_w[c*OT+oo]
  __shared__ uint32_t s_bw[NH_ * 34];  // bit window: words tb/32-1 .. tb/32+32
  __shared__ int s_e[NH_];
  __shared__ float s_f[NH_];
  __shared__ float s_omf[NH_];

  int tid = threadIdx.x;
  int tb = blockIdx.x * 1024;
  int otile = blockIdx.y * OT;
  int b = blockIdx.z;

  // stage transposed weights
  for (int i = tid; i < NH_ * OT; i += 256) {
    int c = i / OT, oo = i % OT;
    s_w[c * OT + oo] = ws[(size_t)(otile + oo) * NH_ + c];
  }
  // stage delay tables
  for (int i = tid; i < NH_; i += 256) {
    s_e[i] = d0c[i];
    float f = fc[i];
    s_f[i] = f;
    s_omf[i] = __fsub_rn(1.0f, f);
  }
  // stage bit window: 34 words per channel, word index w0+k, zero if OOB
  {
    int w0 = tb / 32 - 1;
    const uint32_t* gb = sbits + (size_t)b * NH_ * 64;
    for (int i = tid; i < NH_ * 34; i += 256) {
      int c = i / 34, k = i % 34;
      int wi = w0 + k;
      s_bw[i] = (wi >= 0 && wi < 64) ? gb[c * 64 + wi] : 0u;
    }
  }
  __syncthreads();

  int t0 = tb + tid * 4;
  float acc[OT][4];
#pragma unroll
  for (int oo = 0; oo < OT; oo++)
#pragma unroll
    for (int j = 0; j < 4; j++) acc[oo][j] = 0.f;

  for (int c = 0; c < NH_; c++) {
    int e = s_e[c];
    float f = s_f[c], omf = s_omf[c];
    int rel = tid * 4 + 31 - e;        // bit position of s[t0-e-1] in window
    int wi = rel >> 5, sh = rel & 31;
    uint32_t lo = s_bw[c * 34 + wi];
    uint32_t hi = s_bw[c * 34 + wi + 1];
    unsigned long long S = (((unsigned long long)hi << 32) | lo) >> sh;
    uint32_t Sl = (uint32_t)S;
    float val[4];
#pragma unroll
    for (int j = 0; j < 4; j++) {
      float b0 = (float)((Sl >> j) & 1u);        // s[t-e-1] tap (weight f)
      float b1 = (float)((Sl >> (j + 1)) & 1u);  // s[t-e]   tap (weight 1-f)
      val[j] = __fmaf_rn(omf, b1, __fmul_rn(f, b0));
    }
#pragma unroll
    for (int oo = 0; oo < OT; oo++) {
      float w = s_w[c * OT + oo];
#pragma unroll
      for (int j = 0; j < 4; j++) acc[oo][j] = __fmaf_rn(w, val[j], acc[oo][j]);
    }
  }

#pragma unroll
  for (int oo = 0; oo < OT; oo++) {
    float* zp = z + ((size_t)b * o_count + otile + oo) * T_ + t0;
    *(float4*)zp = make_float4(acc[oo][0], acc[oo][1], acc[oo][2], acc[oo][3]);
  }
}

// ---------------------------------------------------------------------------
// Loihi scan, bitpacked u32 output (UNSHIFTED). One thread per (b,o) row.
// 64-t groups, 4 rotating prefetch buffers (2 groups in flight).
// count = popcount(all bits) - bit[T-1].
// ---------------------------------------------------------------------------
__global__ __launch_bounds__(64, 1) void scan_bits_kernel(const float* __restrict__ z,
                                                          uint32_t* __restrict__ sbits,
                                                          float* __restrict__ cnt) {
  int row = blockIdx.x * 64 + threadIdx.x;
  const float4* zp4 = (const float4*)(z + (size_t)row * T_);
  uint32_t* sp = sbits + (size_t)row * 64;

  float u = 0.f, v = 0.f;
  int ci = 0;
  unsigned long long mlast = 0;
  float4 buf[4][16];

#pragma unroll
  for (int i = 0; i < 16; i++) buf[0][i] = zp4[i];
#pragma unroll
  for (int i = 0; i < 16; i++) buf[1][i] = zp4[16 + i];

#pragma unroll 4
  for (int g = 0; g < 32; g++) {
    int gl = g + 2 > 31 ? 31 : g + 2;
#pragma unroll
    for (int i = 0; i < 16; i++) buf[(g + 2) & 3][i] = zp4[gl * 16 + i];

    unsigned long long m = 0;
#pragma unroll
    for (int i = 0; i < 16; i++) {
      float4 cv = buf[g & 3][i];
      float zv[4] = {cv.x, cv.y, cv.z, cv.w};
#pragma unroll
      for (int j = 0; j < 4; j++) {
        u = addrn(mulrn(ALPHA_I_, u), zv[j]);
        v = addrn(mulrn(ALPHA_V_, v), u);
        bool sb = (v >= THETA_);
        v = sb ? 0.f : v;
        m |= sb ? (1ull << (i * 4 + j)) : 0ull;
      }
    }
    ((uint2*)sp)[g] = make_uint2((uint32_t)m, (uint32_t)(m >> 32));
    ci += __popcll(m);
    mlast = m;
  }
  ci -= (int)(mlast >> 63);  // exclude t = T-1 (delay_shift1 drops it)

  float c = (float)ci;
  for (int off = 32; off; off >>= 1) c += __shfl_down(c, off, 64);
  if (threadIdx.x == 0) atomicAdd(cnt, c);
}

// ---------------------------------------------------------------------------
// Loihi scan, f32 SHIFTED output straight into d_out (layer 3).
// carry chain: out[t] = s_{t-1}; float4-packed stores.
// ---------------------------------------------------------------------------
__global__ __launch_bounds__(64, 1) void scan_f32_kernel(const float* __restrict__ z,
                                                         float* __restrict__ out,
                                                         float* __restrict__ cnt) {
  int row = blockIdx.x * 64 + threadIdx.x;
  const float4* zp4 = (const float4*)(z + (size_t)row * T_);
  float4* op4 = (float4*)(out + (size_t)row * T_);

  float u = 0.f, v = 0.f, carry = 0.f;
  int ci = 0;
  float4 buf[4][16];

#pragma unroll
  for (int i = 0; i < 16; i++) buf[0][i] = zp4[i];
#pragma unroll
  for (int i = 0; i < 16; i++) buf[1][i] = zp4[16 + i];

#pragma unroll 4
  for (int g = 0; g < 32; g++) {
    int gl = g + 2 > 31 ? 31 : g + 2;
#pragma unroll
    for (int i = 0; i < 16; i++) buf[(g + 2) & 3][i] = zp4[gl * 16 + i];

#pragma unroll
    for (int i = 0; i < 16; i++) {
      float4 cv = buf[g & 3][i];
      float zv[4] = {cv.x, cv.y, cv.z, cv.w};
      float ov[4];
#pragma unroll
      for (int j = 0; j < 4; j++) {
        ov[j] = carry;
        ci += (carry > 0.5f) ? 1 : 0;
        u = addrn(mulrn(ALPHA_I_, u), zv[j]);
        v = addrn(mulrn(ALPHA_V_, v), u);
        bool sb = (v >= THETA_);
        v = sb ? 0.f : v;
        carry = sb ? 1.f : 0.f;
      }
      op4[g * 16 + i] = make_float4(ov[0], ov[1], ov[2], ov[3]);
    }
  }

  float c = (float)ci;
  for (int off = 32; off; off >>= 1) c += __shfl_down(c, off, 64);
  if (threadIdx.x == 0) atomicAdd(cnt, c);
}

// ---------------------------------------------------------------------------
extern "C" void kernel_launch(void* const* d_in, const int* in_sizes, int n_in,
                              void* d_out, int out_size, void* d_ws, size_t ws_size,
                              hipStream_t stream) {
  (void)in_sizes; (void)n_in; (void)out_size; (void)ws_size;
  const float* spike  = (const float*)d_in[0];
  const float* fc1_v  = (const float*)d_in[1];
  const float* fc1_g  = (const float*)d_in[2];
  const float* fc2_v  = (const float*)d_in[3];
  const float* fc2_g  = (const float*)d_in[4];
  const float* fc3_v  = (const float*)d_in[5];
  const float* fc3_g  = (const float*)d_in[6];
  const float* delay1 = (const float*)d_in[7];
  const float* delay2 = (const float*)d_in[8];
  float* out = (float*)d_out;

  float* ws   = (float*)d_ws;
  float* w1s  = ws;                         // 2048 floats
  float* w2s  = w1s + 2048;                 // 16384
  float* w3s  = w2s + 16384;                // 640
  int*   d01  = (int*)(w3s + 640);          // 128
  float* f1   = (float*)(d01 + 128);        // 128
  int*   d02  = (int*)(f1 + 128);           // 128
  float* f2   = (float*)(d02 + 128);        // 128
  float* zbuf = ws + 20480;                 // B*NH*T floats, 16B-aligned
  uint32_t* sbits = (uint32_t*)(zbuf + (size_t)B_ * NH_ * T_);  // B*NH*64 u32
  float* counts = out + (size_t)B_ * NOUT_ * T_;

  prep_kernel<<<1, 128, 0, stream>>>(fc1_v, fc1_g, fc2_v, fc2_g, fc3_v, fc3_g,
                                     delay1, delay2, w1s, w2s, w3s, d01, f1, d02, f2, counts);

  // layer 1
  gemm1_kernel<<<dim3(T_ / 256, B_), 256, 0, stream>>>(spike, w1s, zbuf);
  scan_bits_kernel<<<dim3(B_ * NH_ / 64), 64, 0, stream>>>(zbuf, sbits, counts + 0);

  // layer 2 (axon delay 1 fused into bit gather)
  gemm_delay_bits_kernel<32><<<dim3(T_ / 1024, NH_ / 32, B_), 256, 0, stream>>>(
      sbits, w2s, d01, f1, zbuf, NH_);
  scan_bits_kernel<<<dim3(B_ * NH_ / 64), 64, 0, stream>>>(zbuf, sbits, counts + 1);

  // layer 3 (axon delay 2 fused into bit gather)
  gemm_delay_bits_kernel<5><<<dim3(T_ / 1024, 1, B_), 256, 0, stream>>>(
      sbits, w3s, d02, f2, zbuf, NOUT_);
  scan_f32_kernel<<<dim3(B_ * NOUT_ / 64), 64, 0, stream>>>(zbuf, out, counts + 2);
}